// Round 5
// baseline (431.925 us; speedup 1.0000x reference)
//
#include <hip/hip_runtime.h>

// Problem constants
#define NB    32
#define CDIM  256
#define HWSZ  4096                 // 64*64
#define NPOS  (NB*HWSZ)            // 131072
#define KCODES 1024
#define QELEMS ((size_t)NB*CDIM*HWSZ)   // 33554432
#define IDX_OFF QELEMS
#define DIFF_OFF (QELEMS + NPOS)
#define EBYTES (32*32768)          // 1 MB pre-arranged fp16 codebook in d_out scratch
#define E2F_OFF (EBYTES/4)         // float offset 262144 for e2 table

// LDS map (stage1)
#define AOFF  0                    // A: [32 kchunks][2 kh][64 rows][16B] = 64 KB
#define BOFF  65536                // B: 2 x 32 KB double buffer
#define X2P   131072               // x2 partials [8][64] f32 = 2 KB
#define X2T   133120               // x2 totals [64] f32
#define MVOFF 133376               // merge vals [8][64] f32 = 2 KB
#define MIOFF 135424               // merge idx  [8][64] i32 = 2 KB
#define LDSSZ 137472

typedef _Float16       f16x8  __attribute__((ext_vector_type(8)));
typedef float          f32x16 __attribute__((ext_vector_type(16)));
typedef unsigned short u16x8  __attribute__((ext_vector_type(8)));

static __device__ inline unsigned short f2h(float f) {
    _Float16 h = (_Float16)f;
    return __builtin_bit_cast(unsigned short, h);
}

// ---------------------------------------------------------------------------
// prep_embed: pre-arranged fp16 codebook, laid out EXACTLY as stage1's B LDS
// tiles so global_load_lds is a linear copy.
// Tile t (32 KB) = k-chunk: t<16 -> eh chunk t; t>=16 -> (el*64) chunk t-16.
// Within tile: byte = kh*16384 + code*16 + sub*2   (kh=(c>>3)&1, sub=c&7).
// Also e2[k] (fp32) and zero diff accumulator.
// ---------------------------------------------------------------------------
__global__ __launch_bounds__(64) void vq_prep_embed(const float* __restrict__ embed,
                                                    float* __restrict__ out) {
    const int k = blockIdx.x;
    const int lane = threadIdx.x;
    const float4 v = *reinterpret_cast<const float4*>(embed + (size_t)k * CDIM + lane * 4);

    unsigned char* __restrict__ ebuf = (unsigned char*)out;

    _Float16 h0 = (_Float16)v.x, h1 = (_Float16)v.y, h2 = (_Float16)v.z, h3 = (_Float16)v.w;
    ushort4 hv = { __builtin_bit_cast(unsigned short, h0), __builtin_bit_cast(unsigned short, h1),
                   __builtin_bit_cast(unsigned short, h2), __builtin_bit_cast(unsigned short, h3) };
    ushort4 lv = { f2h((v.x - (float)h0) * 64.0f), f2h((v.y - (float)h1) * 64.0f),
                   f2h((v.z - (float)h2) * 64.0f), f2h((v.w - (float)h3) * 64.0f) };

    const int c0   = lane * 4;
    const int tile = c0 >> 4;            // k-chunk 0..15
    const int kh   = (c0 >> 3) & 1;
    const int sub  = c0 & 7;
    const size_t byte = (size_t)tile * 32768 + (size_t)kh * 16384 + (size_t)k * 16 + sub * 2;
    *reinterpret_cast<ushort4*>(ebuf + byte)              = hv;   // eh
    *reinterpret_cast<ushort4*>(ebuf + byte + 16 * 32768) = lv;   // el*64

    float s = v.x * v.x + v.y * v.y + v.z * v.z + v.w * v.w;
    #pragma unroll
    for (int m = 1; m < 64; m <<= 1) s += __shfl_xor(s, m, 64);
    if (lane == 0) out[E2F_OFF + k] = s;
    if (k == 0 && lane == 0) out[DIFF_OFF] = 0.0f;
}

// ---------------------------------------------------------------------------
// stage1: fused fp16-split 32x32x16 MFMA distance + argmin + diff.
// 512 threads = 8 waves; every wave covers all 64 positions x its 128 codes.
// Virtual K=768: seg0 xh*eh | seg1 (xh/64)*(el*64) | seg2 (xl*64)*(eh/64).
// Single fp32 accumulator acc[2][4] (f32x16 each).
// A LDS transposed [kchunk][kh][row][16B] — conflict-free ds_read_b128.
// B LDS [kh][code][16B] — conflict-free; staged via global_load_lds (linear).
// ---------------------------------------------------------------------------
__global__ __launch_bounds__(512, 2) void vq_stage1(const float* __restrict__ x,
                                                    float* __restrict__ out) {
    __shared__ __align__(16) unsigned char lds[LDSSZ];

    const unsigned char* __restrict__ ebuf = (const unsigned char*)out;
    const float* __restrict__ e2buf = out + E2F_OFF;
    float* __restrict__ idx_out = out + IDX_OFF;

    const int t     = threadIdx.x;
    const int lane  = t & 63;
    const int col32 = lane & 31;
    const int hi    = lane >> 5;
    const int widx  = t >> 6;          // wave 0..7 : code group of 128

    const int pos0 = blockIdx.x * 64;
    const int n    = pos0 >> 12;
    const int hw0  = pos0 & 4095;
    const float* __restrict__ xbase = x + (size_t)n * (CDIM * HWSZ) + hw0;

    // ---- A staging: x fp32 -> fp16 (xh | xl*64), transposed layout; x2 partials
    {
        const int i = t & 63;          // position row (coalesced on global read)
        const int g = t >> 6;          // channel group (32 ch)
        float x2p = 0.f;
        #pragma unroll
        for (int j = 0; j < 4; ++j) {
            const int c0 = g * 32 + j * 8;
            u16x8 hv, lv;
            #pragma unroll
            for (int q = 0; q < 8; ++q) {
                float vv = xbase[(size_t)(c0 + q) * HWSZ + i];
                x2p = fmaf(vv, vv, x2p);
                _Float16 hh = (_Float16)vv;
                hv[q] = __builtin_bit_cast(unsigned short, hh);
                lv[q] = f2h((vv - (float)hh) * 64.0f);
            }
            const int a  = c0 >> 4;
            const int kh = (c0 >> 3) & 1;
            const int byte = a * 2048 + kh * 1024 + i * 16;
            *reinterpret_cast<u16x8*>(lds + byte)         = hv;   // xh
            *reinterpret_cast<u16x8*>(lds + byte + 32768) = lv;   // xl*64
        }
        ((float*)(lds + X2P))[g * 64 + i] = x2p;
    }

    // ---- async B staging (linear copy: source pre-arranged)
    auto stage = [&](int tile, int buf) {
        const unsigned char* src = ebuf + (size_t)tile * 32768;
        unsigned char* dst = lds + BOFF + buf * 32768;
        #pragma unroll
        for (int ii = 0; ii < 4; ++ii) {
            const int chunk = (widx * 4 + ii) * 1024;
            __builtin_amdgcn_global_load_lds(
                (const __attribute__((address_space(1))) unsigned int*)(src + chunk + lane * 16),
                (__attribute__((address_space(3))) unsigned int*)(dst + chunk),
                16, 0, 0);
        }
    };

    stage(0, 0);
    __syncthreads();   // A + x2 partials + tile0 resident

    // x2 totals (wave 0 only; consumed after final barrier)
    if (t < 64) {
        const float* p = (const float*)(lds + X2P);
        float s = 0.f;
        #pragma unroll
        for (int g = 0; g < 8; ++g) s += p[g * 64 + t];
        ((float*)(lds + X2T))[t] = s;
    }

    f32x16 acc[2][4];
    #pragma unroll
    for (int ra = 0; ra < 2; ++ra)
        #pragma unroll
        for (int cb = 0; cb < 4; ++cb)
            #pragma unroll
            for (int r = 0; r < 16; ++r) acc[ra][cb][r] = 0.f;

    // loop-invariant lane offsets
    const int aoff_lane = hi * 1024 + col32 * 16;                 // + ra*512
    const int boff_lane = hi * 16384 + (widx * 128 + col32) * 16; // + cb*512

    int buf = 0;
    for (int kq = 0; kq < 48; ++kq) {
        const int nb = kq + 1;
        if (nb < 48) stage(nb < 32 ? nb : nb - 32, buf ^ 1);

        const int a = (kq < 16) ? kq : kq - 16;   // xh twice, then xl*64
        const unsigned char* ab = lds + a * 2048;
        const unsigned char* bb = lds + BOFF + buf * 32768;

        f16x8 av[2], bv[4];
        #pragma unroll
        for (int ra = 0; ra < 2; ++ra)
            av[ra] = *reinterpret_cast<const f16x8*>(ab + aoff_lane + ra * 512);
        #pragma unroll
        for (int cb = 0; cb < 4; ++cb)
            bv[cb] = *reinterpret_cast<const f16x8*>(bb + boff_lane + cb * 512);

        if (kq >= 16 && kq < 32) {       // seg1: scale A by 1/64 (exact pow2)
            #pragma unroll
            for (int ra = 0; ra < 2; ++ra) av[ra] *= (_Float16)0.015625f;
        } else if (kq >= 32) {           // seg2: scale B by 1/64
            #pragma unroll
            for (int cb = 0; cb < 4; ++cb) bv[cb] *= (_Float16)0.015625f;
        }

        __builtin_amdgcn_s_setprio(1);
        #pragma unroll
        for (int ra = 0; ra < 2; ++ra)
            #pragma unroll
            for (int cb = 0; cb < 4; ++cb)
                acc[ra][cb] = __builtin_amdgcn_mfma_f32_32x32x16_f16(
                    av[ra], bv[cb], acc[ra][cb], 0, 0, 0);
        __builtin_amdgcn_s_setprio(0);

        __syncthreads();   // drains prefetch + LDS reads before buffer swap
        buf ^= 1;
    }

    // ---- epilogue: scores, per-wave argmin, cross-wave merge
    const float* x2t = (const float*)(lds + X2T);
    float e2v[4];
    #pragma unroll
    for (int cb = 0; cb < 4; ++cb)
        e2v[cb] = e2buf[widx * 128 + cb * 32 + col32];

    float* mv = (float*)(lds + MVOFF);
    int*   mi = (int*)(lds + MIOFF);

    #pragma unroll
    for (int ra = 0; ra < 2; ++ra) {
        #pragma unroll
        for (int reg = 0; reg < 16; ++reg) {
            const int pos = ra * 32 + (reg & 3) + 8 * (reg >> 2) + 4 * hi;
            const float x2 = x2t[pos];
            float bv_ = 3.4e38f;
            int   bi_ = 0;
            #pragma unroll
            for (int cb = 0; cb < 4; ++cb) {
                const int code = widx * 128 + cb * 32 + col32;
                const float s = (x2 - 2.0f * acc[ra][cb][reg]) + e2v[cb];
                if (s < bv_) { bv_ = s; bi_ = code; }
            }
            // shuffle-merge over the 32 code columns (masks < 32 stay in half)
            #pragma unroll
            for (int m = 1; m < 32; m <<= 1) {
                float ov = __shfl_xor(bv_, m, 64);
                int   oi = __shfl_xor(bi_, m, 64);
                if (ov < bv_ || (ov == bv_ && oi < bi_)) { bv_ = ov; bi_ = oi; }
            }
            if (col32 == 0) {
                mv[widx * 64 + pos] = bv_;
                mi[widx * 64 + pos] = bi_;
            }
        }
    }

    __syncthreads();
    if (t < 64) {
        float bv_ = mv[t];
        int   bi_ = mi[t];
        #pragma unroll
        for (int w = 1; w < 8; ++w) {
            const float ov = mv[w * 64 + t];
            const int   oi = mi[w * 64 + t];
            if (ov < bv_ || (ov == bv_ && oi < bi_)) { bv_ = ov; bi_ = oi; }
        }
        idx_out[pos0 + t] = (float)bi_;
        // diff partial = sum of min distances
        float d = bv_;
        #pragma unroll
        for (int m = 1; m < 64; m <<= 1) d += __shfl_xor(d, m, 64);
        if (t == 0) atomicAdd(out + DIFF_OFF, d * (1.0f / 33554432.0f));
    }
}

// ---------------------------------------------------------------------------
// gather: quantize = embed[idx] (NCHW). Diff already done in stage1.
// ---------------------------------------------------------------------------
__global__ __launch_bounds__(256) void vq_gather_kernel(const float* __restrict__ embed,
                                                        float* __restrict__ out) {
    const int tid = threadIdx.x;
    const int p = blockIdx.x * 256 + tid;
    const int n = p >> 12;
    const int hw = p & 4095;
    const int idx = (int)out[IDX_OFF + p];
    const float4* __restrict__ erow4 = reinterpret_cast<const float4*>(embed + (size_t)idx * CDIM);
    float* __restrict__ op = out + (size_t)n * (CDIM * HWSZ) + hw;

    #pragma unroll 8
    for (int c4 = 0; c4 < 64; ++c4) {
        const float4 e = erow4[c4];
        op[(size_t)(c4 * 4 + 0) * HWSZ] = e.x;
        op[(size_t)(c4 * 4 + 1) * HWSZ] = e.y;
        op[(size_t)(c4 * 4 + 2) * HWSZ] = e.z;
        op[(size_t)(c4 * 4 + 3) * HWSZ] = e.w;
    }
}

extern "C" void kernel_launch(void* const* d_in, const int* in_sizes, int n_in,
                              void* d_out, int out_size, void* d_ws, size_t ws_size,
                              hipStream_t stream) {
    const float* x = (const float*)d_in[0];
    const float* embed = (const float*)d_in[1];
    float* out = (float*)d_out;

    vq_prep_embed<<<KCODES, 64, 0, stream>>>(embed, out);
    vq_stage1<<<NPOS / 64, 512, 0, stream>>>(x, out);
    vq_gather_kernel<<<NPOS / 256, 256, 0, stream>>>(embed, out);
}